// Round 1
// baseline (1076.913 us; speedup 1.0000x reference)
//
#include <hip/hip_runtime.h>

// SpectralConv3d (FNO layer): B=4, Cin=Cout=64, D=H=W=64, modes=(16,16,16)
// Strategy: truncated separable DFTs instead of full FFTs.
//   fwd:  x (B,Ci,64,64,64) --W,H--> T1 (B,Ci,64,16,16)c --D--> T2 (B,Ci,16,16,16)c
//   mix:  MX[b,o,m] = sum_i T2[b,i,m] * wgt[i,o,m]   (real weights)
//   inv:  MX --D--> O1 (B,Co,64,16,16)c --H,W--> out (B,Co,64,64,64) + bias
// Normalization 1/64^3 folded into the last kernel.

#define ANG (0.09817477042468103f)   // 2*pi/64

__device__ __forceinline__ void make_twiddles(float* tc, float* ts) {
  int t = threadIdx.x;
  if (t < 64) {
    float s, c;
    sincosf(ANG * (float)t, &s, &c);
    tc[t] = c; ts[t] = s;
  }
}

// ---------------- forward: W then H truncated DFT per (b,ci,d) slice --------
__global__ __launch_bounds__(256) void k_fwd_hw(const float* __restrict__ x,
                                                float2* __restrict__ T1) {
  __shared__ float xs[64][65];
  __shared__ float ir[64][16];
  __shared__ float ii[64][16];
  __shared__ float tc[64], ts[64];
  const int t = threadIdx.x;
  const int blk = blockIdx.x;                 // (b*64+ci)*64 + d
  make_twiddles(tc, ts);
  const float* xg = x + (size_t)blk * 4096;
#pragma unroll
  for (int j = 0; j < 4; ++j) {               // coalesced float4 load of 64x64
    int v = j * 256 + t;
    float4 val = reinterpret_cast<const float4*>(xg)[v];
    int row = v >> 4;
    int col = (v & 15) * 4;
    xs[row][col]     = val.x;
    xs[row][col + 1] = val.y;
    xs[row][col + 2] = val.z;
    xs[row][col + 3] = val.w;
  }
  __syncthreads();
  // step 1: W axis, real -> complex, 64 -> 16 freqs
  {
    const int k  = t & 15;
    const int r0 = t >> 4;
#pragma unroll
    for (int pass = 0; pass < 4; ++pass) {
      int row = r0 + pass * 16;
      float ar = 0.f, ai = 0.f;
      for (int w = 0; w < 64; ++w) {
        float v = xs[row][w];
        int m = (w * k) & 63;
        ar = fmaf(v, tc[m], ar);
        ai = fmaf(v, -ts[m], ai);
      }
      ir[row][k] = ar; ii[row][k] = ai;
    }
  }
  __syncthreads();
  // step 2: H axis, complex 64 -> 16, multiply by e^{-2*pi*i*ky*r/64}
  {
    const int kz = t & 15, ky = t >> 4;
    float ar = 0.f, ai = 0.f;
    for (int r = 0; r < 64; ++r) {
      int m = (r * ky) & 63;
      float c = tc[m], s = ts[m];
      float xr = ir[r][kz], xi = ii[r][kz];
      ar += xr * c + xi * s;
      ai += xi * c - xr * s;
    }
    T1[(size_t)blk * 256 + t] = make_float2(ar, ai);
  }
}

// ---------------- forward: D axis 64 -> 16 -------------------------------
__global__ __launch_bounds__(256) void k_fwd_d(const float2* __restrict__ T1,
                                               float2* __restrict__ T2) {
  __shared__ float tc[64], ts[64];
  make_twiddles(tc, ts);
  __syncthreads();
  const int t  = threadIdx.x;
  const int ky = blockIdx.x & 15;
  const int bi = blockIdx.x >> 4;
  const int kx = t >> 4, kz = t & 15;
  const float2* src = T1 + (size_t)bi * 16384 + ky * 16;  // [d][ky][kz]
  float ar = 0.f, ai = 0.f;
  for (int d = 0; d < 64; ++d) {
    float2 v = src[d * 256 + kz];
    int m = (d * kx) & 63;
    float c = tc[m], s = ts[m];
    ar += v.x * c + v.y * s;
    ai += v.y * c - v.x * s;
  }
  T2[(size_t)bi * 4096 + kx * 256 + ky * 16 + kz] = make_float2(ar, ai);
}

// ---------------- channel mix: MX[b,o,m] = sum_i T2[b,i,m]*w[i,o,m] ------
__global__ __launch_bounds__(256) void k_mix(const float2* __restrict__ T2,
                                             const float* __restrict__ wgt,
                                             float2* __restrict__ MX) {
  // grid = B*64; block: 64 modes x 4 o-groups (16 o each)
  const int t = threadIdx.x;
  const int b = blockIdx.x >> 6;
  const int mode = ((blockIdx.x & 63) << 6) + (t & 63);
  const int og = t >> 6;                       // o = og*16 + j
  const float2* xin = T2 + (size_t)b * 64 * 4096;
  float accr[16], acci[16];
#pragma unroll
  for (int j = 0; j < 16; ++j) { accr[j] = 0.f; acci[j] = 0.f; }
  for (int i = 0; i < 64; ++i) {
    float2 xv = xin[(size_t)i * 4096 + mode];
    const float* wp = wgt + ((size_t)i * 64 + og * 16) * 4096 + mode;
#pragma unroll
    for (int j = 0; j < 16; ++j) {
      float wv = wp[(size_t)j * 4096];
      accr[j] = fmaf(xv.x, wv, accr[j]);
      acci[j] = fmaf(xv.y, wv, acci[j]);
    }
  }
  float2* outp = MX + (size_t)b * 64 * 4096 + mode;
#pragma unroll
  for (int j = 0; j < 16; ++j)
    outp[(size_t)(og * 16 + j) * 4096] = make_float2(accr[j], acci[j]);
}

// ---------------- inverse: D axis 16 -> 64 (e^{+i}) ----------------------
__global__ __launch_bounds__(256) void k_inv_d(const float2* __restrict__ MX,
                                               float2* __restrict__ O1) {
  __shared__ float tc[64], ts[64];
  make_twiddles(tc, ts);
  __syncthreads();
  const int t  = threadIdx.x;                 // (ky,kz)
  const int bo = blockIdx.x >> 2;
  const int d0 = (blockIdx.x & 3) * 16;
  const float2* src = MX + (size_t)bo * 4096;
  float cr[16], ci[16];
#pragma unroll
  for (int kx = 0; kx < 16; ++kx) {
    float2 v = src[kx * 256 + t];
    cr[kx] = v.x; ci[kx] = v.y;
  }
  float2* dst = O1 + (size_t)bo * 16384;
  for (int dd = 0; dd < 16; ++dd) {
    int d = d0 + dd;
    float ar = 0.f, ai = 0.f;
#pragma unroll
    for (int kx = 0; kx < 16; ++kx) {
      int m = (d * kx) & 63;
      float c = tc[m], s = ts[m];
      ar += cr[kx] * c - ci[kx] * s;
      ai += cr[kx] * s + ci[kx] * c;
    }
    dst[(size_t)d * 256 + t] = make_float2(ar, ai);
  }
}

// ---------------- inverse: H (16->64 complex) then W (Hermitian 16->64 real)
__global__ __launch_bounds__(256) void k_inv_hw(const float2* __restrict__ O1,
                                                const float* __restrict__ bias,
                                                float* __restrict__ out) {
  __shared__ float gr[64][17], gi[64][17];
  __shared__ float tc[64], ts[64];
  __shared__ float2 inb[256];
  const int t = threadIdx.x;
  const int blk = blockIdx.x;                 // (b*64+o)*64 + d
  make_twiddles(tc, ts);
  inb[t] = O1[(size_t)blk * 256 + t];
  __syncthreads();
  // H expansion: g[h][kz] = sum_ky inb[ky][kz] * e^{+2*pi*i*h*ky/64}
  {
    const int kz = t & 15;
    const int h0 = t >> 4;
#pragma unroll
    for (int pass = 0; pass < 4; ++pass) {
      int h = h0 + pass * 16;
      float ar = 0.f, ai = 0.f;
#pragma unroll
      for (int ky = 0; ky < 16; ++ky) {
        int m = (h * ky) & 63;
        float c = tc[m], s = ts[m];
        float2 v = inb[ky * 16 + kz];
        ar += v.x * c - v.y * s;
        ai += v.x * s + v.y * c;
      }
      gr[h][kz] = ar; gi[h][kz] = ai;
    }
  }
  __syncthreads();
  // W inverse (Hermitian):  x[w] = Re(g0) + 2*sum_{k=1..15} Re(gk * e^{+2*pi*i*k*w/64})
  const int o  = (blk >> 6) & 63;
  const float bv = bias[o];
  const float scale = 3.814697265625e-06f;    // 1 / 64^3
  float* og = out + (size_t)blk * 4096;
  const int w0 = (t & 15) * 4;
#pragma unroll
  for (int pass = 0; pass < 4; ++pass) {
    int h = (t >> 4) + pass * 16;
    float r0, r1, r2, r3;
    {
      float acc0 = gr[h][0], acc1 = gr[h][0], acc2 = gr[h][0], acc3 = gr[h][0];
#pragma unroll
      for (int k = 1; k < 16; ++k) {
        float grv = 2.f * gr[h][k], giv = 2.f * gi[h][k];
        int m0 = (k * (w0 + 0)) & 63;
        int m1 = (k * (w0 + 1)) & 63;
        int m2 = (k * (w0 + 2)) & 63;
        int m3 = (k * (w0 + 3)) & 63;
        acc0 += grv * tc[m0] - giv * ts[m0];
        acc1 += grv * tc[m1] - giv * ts[m1];
        acc2 += grv * tc[m2] - giv * ts[m2];
        acc3 += grv * tc[m3] - giv * ts[m3];
      }
      r0 = fmaf(acc0, scale, bv);
      r1 = fmaf(acc1, scale, bv);
      r2 = fmaf(acc2, scale, bv);
      r3 = fmaf(acc3, scale, bv);
    }
    float4 res = make_float4(r0, r1, r2, r3);
    reinterpret_cast<float4*>(og + h * 64)[t & 15] = res;
  }
}

extern "C" void kernel_launch(void* const* d_in, const int* in_sizes, int n_in,
                              void* d_out, int out_size, void* d_ws, size_t ws_size,
                              hipStream_t stream) {
  const float* x    = (const float*)d_in[0];   // (4,64,64,64,64)
  const float* wgt  = (const float*)d_in[1];   // (64,64,16,16,16)
  const float* bias = (const float*)d_in[2];   // (64,)
  float* out = (float*)d_out;                  // (4,64,64,64,64)

  float* wsf = (float*)d_ws;
  float2* T1 = (float2*)wsf;                       // 4,194,304 float2 (33.5 MB)
  float2* T2 = (float2*)(wsf + 8388608);           // 1,048,576 float2 ( 8.4 MB)
  float2* MX = (float2*)(wsf + 8388608 + 2097152); // 1,048,576 float2 ( 8.4 MB)
  float2* O1 = T1;                                 // alias: T1 dead after k_fwd_d

  k_fwd_hw<<<16384, 256, 0, stream>>>(x, T1);      // (b,ci,d) slices
  k_fwd_d <<<4096,  256, 0, stream>>>(T1, T2);     // (b,ci,ky)
  k_mix   <<<256,   256, 0, stream>>>(T2, wgt, MX);// (b, mode-block)
  k_inv_d <<<1024,  256, 0, stream>>>(MX, O1);     // (b,co, d-quarter)
  k_inv_hw<<<16384, 256, 0, stream>>>(O1, bias, out); // (b,co,d) slices
}

// Round 2
// 700.580 us; speedup vs baseline: 1.5372x; 1.5372x over previous
//
#include <hip/hip_runtime.h>

// SpectralConv3d (FNO): B=4, Cin=Cout=64, D=H=W=64, modes=(16,16,16)
// Truncated separable DFTs; twiddles via complex recurrence (no LDS table in hot loops).
//   fwd:  x --W,H (k_fwd_hw)--> T1 (B,Ci,64,16,16)c --D (k_fwd_d)--> T2 (B,Ci,16³)c
//   mix:  MX[b,o,m] = sum_i T2[b,i,m] * wgt[i,o,m]
//   inv (fused): MX --D-expand(regs)--> --H-expand(LDS)--> --W Hermitian--> out + bias

#define ANG 0.09817477042468103f   // 2*pi/64
#define C1W 0.9951847266721969f    // cos(2*pi/64)
#define S1W 0.0980171403295606f    // sin(2*pi/64)

// ---------------- forward: W then H truncated DFT per (b,ci,d) slice --------
__global__ __launch_bounds__(256) void k_fwd_hw(const float* __restrict__ x,
                                                float2* __restrict__ T1) {
  __shared__ float xs[64][68];       // padded, 16B-aligned rows
  __shared__ float2 irc[64][17];     // interleaved (re,im), padded
  const int t = threadIdx.x;
  const int blk = blockIdx.x;        // (b*64+ci)*64 + d
  const float* xg = x + (size_t)blk * 4096;
#pragma unroll
  for (int j = 0; j < 4; ++j) {      // coalesced float4 load of 64x64
    int v = j * 256 + t;
    float4 val = reinterpret_cast<const float4*>(xg)[v];
    *reinterpret_cast<float4*>(&xs[v >> 4][(v & 15) * 4]) = val;
  }
  __syncthreads();
  // step 1: W axis real->complex 64->16. thread: k=t&15, rows 4g..4g+3
  {
    const int k = t & 15;
    const int g = t >> 4;
    float s1, c1;
    sincosf(ANG * (float)k, &s1, &c1);
    s1 = -s1;                                    // e^{-i*th*k}
    const float c2 = c1 * c1 - s1 * s1;          // e^{-2i*th*k}
    const float s2 = 2.f * c1 * s1;
    float cw = 1.f, sw = 0.f;                    // twiddle at even w
    float ar0=0,ai0=0,ar1=0,ai1=0,ar2=0,ai2=0,ar3=0,ai3=0;
    const float2* r0 = reinterpret_cast<const float2*>(&xs[4*g+0][0]);
    const float2* r1 = reinterpret_cast<const float2*>(&xs[4*g+1][0]);
    const float2* r2 = reinterpret_cast<const float2*>(&xs[4*g+2][0]);
    const float2* r3 = reinterpret_cast<const float2*>(&xs[4*g+3][0]);
#pragma unroll 8
    for (int w2 = 0; w2 < 32; ++w2) {
      float2 v0 = r0[w2], v1 = r1[w2], v2 = r2[w2], v3 = r3[w2];
      float co = cw * c1 - sw * s1;              // odd-w twiddle
      float so = sw * c1 + cw * s1;
      ar0 = fmaf(v0.x, cw, ar0); ai0 = fmaf(v0.x, sw, ai0);
      ar1 = fmaf(v1.x, cw, ar1); ai1 = fmaf(v1.x, sw, ai1);
      ar2 = fmaf(v2.x, cw, ar2); ai2 = fmaf(v2.x, sw, ai2);
      ar3 = fmaf(v3.x, cw, ar3); ai3 = fmaf(v3.x, sw, ai3);
      ar0 = fmaf(v0.y, co, ar0); ai0 = fmaf(v0.y, so, ai0);
      ar1 = fmaf(v1.y, co, ar1); ai1 = fmaf(v1.y, so, ai1);
      ar2 = fmaf(v2.y, co, ar2); ai2 = fmaf(v2.y, so, ai2);
      ar3 = fmaf(v3.y, co, ar3); ai3 = fmaf(v3.y, so, ai3);
      float nc = cw * c2 - sw * s2;              // advance by 2 steps
      sw = sw * c2 + cw * s2;
      cw = nc;
    }
    irc[4*g+0][k] = make_float2(ar0, ai0);
    irc[4*g+1][k] = make_float2(ar1, ai1);
    irc[4*g+2][k] = make_float2(ar2, ai2);
    irc[4*g+3][k] = make_float2(ar3, ai3);
  }
  __syncthreads();
  // step 2: H axis complex 64->16. thread: kz=t&15, ky=t>>4
  {
    const int kz = t & 15, ky = t >> 4;
    float s1, c1;
    sincosf(ANG * (float)ky, &s1, &c1);
    s1 = -s1;                                    // e^{-i*th*ky}
    float cw = 1.f, sw = 0.f, ar = 0.f, ai = 0.f;
#pragma unroll 8
    for (int r = 0; r < 64; ++r) {
      float2 v = irc[r][kz];
      ar += v.x * cw - v.y * sw;
      ai += v.y * cw + v.x * sw;
      float nc = cw * c1 - sw * s1;
      sw = sw * c1 + cw * s1;
      cw = nc;
    }
    T1[(size_t)blk * 256 + t] = make_float2(ar, ai);   // [d][ky][kz]
  }
}

// ---------------- forward: D axis 64 -> 16, one block per (b,i) -----------
__global__ __launch_bounds__(256) void k_fwd_d(const float2* __restrict__ T1,
                                               float2* __restrict__ T2) {
  __shared__ float2 tw[64];
  const int t = threadIdx.x;
  if (t < 64) {
    float s, c; sincosf(ANG * (float)t, &s, &c);
    tw[t] = make_float2(c, s);
  }
  __syncthreads();
  const int bi = blockIdx.x;                      // b*64 + i
  const float2* src = T1 + (size_t)bi * 16384 + t;
  float ar[16], ai[16];
#pragma unroll
  for (int q = 0; q < 16; ++q) { ar[q] = 0.f; ai[q] = 0.f; }
#pragma unroll 4
  for (int d = 0; d < 64; ++d) {
    float2 v = src[(size_t)d * 256];              // coalesced, read-once
    int m = 0;
#pragma unroll
    for (int kx = 0; kx < 16; ++kx) {             // e^{-i th d kx}
      float2 w = tw[m];                           // wave-uniform -> broadcast
      ar[kx] = fmaf(v.x, w.x, fmaf(v.y, w.y, ar[kx]));
      ai[kx] = fmaf(v.y, w.x, fmaf(-v.x, w.y, ai[kx]));
      m = (m + d) & 63;
    }
  }
  float2* dst = T2 + (size_t)bi * 4096 + t;
#pragma unroll
  for (int kx = 0; kx < 16; ++kx)
    dst[(size_t)kx * 256] = make_float2(ar[kx], ai[kx]);
}

// ---------------- channel mix: MX[b,o,m] = sum_i T2[b,i,m]*w[i,o,m] ------
__global__ __launch_bounds__(256) void k_mix(const float2* __restrict__ T2,
                                             const float* __restrict__ wgt,
                                             float2* __restrict__ MX) {
  const int t = threadIdx.x;
  const int b = blockIdx.x >> 6;
  const int mode = ((blockIdx.x & 63) << 6) + (t & 63);
  const int og = t >> 6;                          // o = og*16 + j
  const float2* xin = T2 + (size_t)b * 64 * 4096;
  float accr[16], acci[16];
#pragma unroll
  for (int j = 0; j < 16; ++j) { accr[j] = 0.f; acci[j] = 0.f; }
  for (int i = 0; i < 64; ++i) {
    float2 xv = xin[(size_t)i * 4096 + mode];
    const float* wp = wgt + ((size_t)i * 64 + og * 16) * 4096 + mode;
#pragma unroll
    for (int j = 0; j < 16; ++j) {
      float wv = wp[(size_t)j * 4096];
      accr[j] = fmaf(xv.x, wv, accr[j]);
      acci[j] = fmaf(xv.y, wv, acci[j]);
    }
  }
  float2* outp = MX + (size_t)b * 64 * 4096 + mode;
#pragma unroll
  for (int j = 0; j < 16; ++j)
    outp[(size_t)(og * 16 + j) * 4096] = make_float2(accr[j], acci[j]);
}

// -------- inverse (fused): D-expand (regs) + H-expand (LDS) + W Hermitian --
__global__ __launch_bounds__(256) void k_inv(const float2* __restrict__ MX,
                                             const float* __restrict__ bias,
                                             float* __restrict__ out) {
  __shared__ float2 tw[64];
  __shared__ float2 inb[16][17];
  __shared__ float2 g2[64][17];
  const int t = threadIdx.x;
  const int blk = blockIdx.x;                     // (b*64+o)*64 + d
  const int d = blk & 63;
  const int bo = blk >> 6;
  if (t < 64) {
    float s, c; sincosf(ANG * (float)t, &s, &c);
    tw[t] = make_float2(c, s);
  }
  __syncthreads();
  // D expansion: inb[ky][kz] = sum_kx MX[bo][kx][ky][kz] * e^{+i th d kx}
  {
    const float2* src = MX + (size_t)bo * 4096 + t;
    float ar = 0.f, ai = 0.f;
    int m = 0;
#pragma unroll
    for (int kx = 0; kx < 16; ++kx) {
      float2 v = src[(size_t)kx * 256];           // coalesced, L2-resident
      float2 w = tw[m];                           // wave-uniform
      ar += v.x * w.x - v.y * w.y;
      ai += v.x * w.y + v.y * w.x;
      m = (m + d) & 63;
    }
    inb[t >> 4][t & 15] = make_float2(ar, ai);
  }
  __syncthreads();
  // H expansion: g2[h][kz] = 2 * sum_ky inb[ky][kz] e^{+i th h ky}, h=4g+j
  {
    const int kz = t & 15, g = t >> 4;
    const int h0 = 4 * g;
    float ar[4] = {0,0,0,0}, ai[4] = {0,0,0,0};
    int m0 = 0, m1 = 0, m2 = 0, m3 = 0;
#pragma unroll
    for (int ky = 0; ky < 16; ++ky) {
      float2 v = inb[ky][kz];
      float2 w0 = tw[m0], w1 = tw[m1], w2 = tw[m2], w3 = tw[m3];
      ar[0] += v.x*w0.x - v.y*w0.y; ai[0] += v.x*w0.y + v.y*w0.x;
      ar[1] += v.x*w1.x - v.y*w1.y; ai[1] += v.x*w1.y + v.y*w1.x;
      ar[2] += v.x*w2.x - v.y*w2.y; ai[2] += v.x*w2.y + v.y*w2.x;
      ar[3] += v.x*w3.x - v.y*w3.y; ai[3] += v.x*w3.y + v.y*w3.x;
      m0 = (m0 + h0    ) & 63; m1 = (m1 + h0 + 1) & 63;
      m2 = (m2 + h0 + 2) & 63; m3 = (m3 + h0 + 3) & 63;
    }
#pragma unroll
    for (int j = 0; j < 4; ++j)
      g2[h0 + j][kz] = make_float2(ar[j] + ar[j], ai[j] + ai[j]);  // pre-x2
  }
  __syncthreads();
  // W Hermitian inverse: x[w] = scale*(0.5*G'[0].re + sum_{k=1..15} Re(G'[k] e^{+i th k w}))
  {
    const int wq = t & 15, hg = t >> 4;
    const int w0 = wq * 4;
    float s0, c0;
    sincosf(ANG * (float)w0, &s0, &c0);
    float stc[4], sts[4];                         // e^{+i th (w0+wi)}
    stc[0] = c0; sts[0] = s0;
    stc[1] = stc[0]*C1W - sts[0]*S1W; sts[1] = sts[0]*C1W + stc[0]*S1W;
    stc[2] = stc[1]*C1W - sts[1]*S1W; sts[2] = sts[1]*C1W + stc[1]*S1W;
    stc[3] = stc[2]*C1W - sts[2]*S1W; sts[3] = sts[2]*C1W + stc[2]*S1W;
    float chc[4], chs[4];
    float acc[4][4];
#pragma unroll
    for (int wi = 0; wi < 4; ++wi) { chc[wi] = stc[wi]; chs[wi] = sts[wi]; }
#pragma unroll
    for (int j = 0; j < 4; ++j) {
      float dc = 0.5f * g2[4*hg + j][0].x;        // DC (imag exactly 0 in exact arith)
#pragma unroll
      for (int wi = 0; wi < 4; ++wi) acc[j][wi] = dc;
    }
#pragma unroll
    for (int kk = 1; kk < 16; ++kk) {
      float2 gv0 = g2[4*hg + 0][kk];
      float2 gv1 = g2[4*hg + 1][kk];
      float2 gv2 = g2[4*hg + 2][kk];
      float2 gv3 = g2[4*hg + 3][kk];
#pragma unroll
      for (int wi = 0; wi < 4; ++wi) {
        float c = chc[wi], s = chs[wi];
        acc[0][wi] = fmaf(gv0.x, c, fmaf(-gv0.y, s, acc[0][wi]));
        acc[1][wi] = fmaf(gv1.x, c, fmaf(-gv1.y, s, acc[1][wi]));
        acc[2][wi] = fmaf(gv2.x, c, fmaf(-gv2.y, s, acc[2][wi]));
        acc[3][wi] = fmaf(gv3.x, c, fmaf(-gv3.y, s, acc[3][wi]));
      }
#pragma unroll
      for (int wi = 0; wi < 4; ++wi) {            // chain *= step
        float nc = chc[wi]*stc[wi] - chs[wi]*sts[wi];
        chs[wi] = chs[wi]*stc[wi] + chc[wi]*sts[wi];
        chc[wi] = nc;
      }
    }
    const float bv = bias[bo & 63];
    const float scale = 3.814697265625e-06f;      // 1/64^3
    float* og = out + (size_t)blk * 4096;
#pragma unroll
    for (int j = 0; j < 4; ++j) {
      float4 res;
      res.x = fmaf(acc[j][0], scale, bv);
      res.y = fmaf(acc[j][1], scale, bv);
      res.z = fmaf(acc[j][2], scale, bv);
      res.w = fmaf(acc[j][3], scale, bv);
      *reinterpret_cast<float4*>(og + (4*hg + j) * 64 + w0) = res;
    }
  }
}

extern "C" void kernel_launch(void* const* d_in, const int* in_sizes, int n_in,
                              void* d_out, int out_size, void* d_ws, size_t ws_size,
                              hipStream_t stream) {
  const float* x    = (const float*)d_in[0];   // (4,64,64,64,64)
  const float* wgt  = (const float*)d_in[1];   // (64,64,16,16,16)
  const float* bias = (const float*)d_in[2];   // (64,)
  float* out = (float*)d_out;                  // (4,64,64,64,64)

  float* wsf = (float*)d_ws;
  float2* T1 = (float2*)wsf;                       // 33.5 MB
  float2* T2 = (float2*)(wsf + 8388608);           //  8.4 MB
  float2* MX = (float2*)(wsf + 8388608 + 2097152); //  8.4 MB

  k_fwd_hw<<<16384, 256, 0, stream>>>(x, T1);
  k_fwd_d <<<256,   256, 0, stream>>>(T1, T2);
  k_mix   <<<256,   256, 0, stream>>>(T2, wgt, MX);
  k_inv   <<<16384, 256, 0, stream>>>(MX, bias, out);
}

// Round 3
// 647.805 us; speedup vs baseline: 1.6624x; 1.0815x over previous
//
#include <hip/hip_runtime.h>

// SpectralConv3d (FNO): B=4, Cin=Cout=64, D=H=W=64, modes=(16,16,16)
// Truncated separable DFTs with radix-4 factorizations.
//   fwd:  x --W(pair),H(radix4)--> T1 (B,Ci,64,16,16)c --D--> T2 (B,Ci,16^3)c
//   mix:  MX[b,o,m] = sum_i T2[b,i,m] * wgt[i,o,m]   (weights read once)
//   inv:  MX --D-expand--> H-expand(radix4) --> W Hermitian(radix4) --> out+bias

#define ANG 0.09817477042468103f   // 2*pi/64

// ---------------- forward: W then H truncated DFT per (b,ci,d) slice --------
__global__ __launch_bounds__(256) void k_fwd_hw(const float* __restrict__ x,
                                                float2* __restrict__ T1) {
  __shared__ float xs[64][68];      // raw slice; later aliased by U
  __shared__ float xpm[64][68];     // [row][w-1]=xp(w) w=1..31, [row][31+w]=xm(w), [63]=x0, [64]=x32
  __shared__ float2 irc[64][17];    // W-stage output (64 rows x 16 k)
  __shared__ float2 tw[64];         // (cos, sin)(2*pi*j/64)
  float2 (*U)[16][17] = reinterpret_cast<float2(*)[16][17]>(&xs[0][0]);  // alias (xs dead)

  const int t = threadIdx.x;
  const int blk = blockIdx.x;       // (b*64+ci)*64 + d
  if (t < 64) { float s, c; sincosf(ANG * (float)t, &s, &c); tw[t] = make_float2(c, s); }
  const float* xg = x + (size_t)blk * 4096;
#pragma unroll
  for (int j = 0; j < 4; ++j) {
    int v = j * 256 + t;
    float4 val = reinterpret_cast<const float4*>(xg)[v];
    *reinterpret_cast<float4*>(&xs[v >> 4][(v & 15) * 4]) = val;
  }
  __syncthreads();
  // pair stage: xp/xm
#pragma unroll
  for (int p = 0; p < 8; ++p) {
    int f = p * 256 + t;
    int row = f >> 5, w = f & 31;
    if (w == 0) { xpm[row][63] = xs[row][0]; xpm[row][64] = xs[row][32]; }
    else {
      float a = xs[row][w], b2 = xs[row][64 - w];
      xpm[row][w - 1] = a + b2;       // xp
      xpm[row][31 + w] = a - b2;      // xm
    }
  }
  __syncthreads();
  // W stage: X[k] = x0 + (-1)^k x32 + sum xp*cos - i*sum xm*sin
  {
    const int k = t & 15, g = t >> 4;
    const int r0 = 4 * g;
    const float x32sign = (k & 1) ? -1.f : 1.f;
    float re[4], im[4];
#pragma unroll
    for (int j = 0; j < 4; ++j) {
      re[j] = fmaf(x32sign, xpm[r0 + j][64], xpm[r0 + j][63]);
      im[j] = 0.f;
    }
#pragma unroll 5
    for (int i = 0; i < 15; ++i) {
      int w = 2 * i + 1;
      float2 tw1 = tw[(k * w) & 63];
      float2 tw2 = tw[(k * (w + 1)) & 63];
#pragma unroll
      for (int j = 0; j < 4; ++j) {
        float2 xp = *reinterpret_cast<const float2*>(&xpm[r0 + j][w - 1]);
        float2 xm = *reinterpret_cast<const float2*>(&xpm[r0 + j][31 + w]);
        re[j] = fmaf(xp.x, tw1.x, re[j]); im[j] = fmaf(xm.x, tw1.y, im[j]);
        re[j] = fmaf(xp.y, tw2.x, re[j]); im[j] = fmaf(xm.y, tw2.y, im[j]);
      }
    }
    { // tail w = 31
      float2 tw1 = tw[(k * 31) & 63];
#pragma unroll
      for (int j = 0; j < 4; ++j) {
        re[j] = fmaf(xpm[r0 + j][30], tw1.x, re[j]);
        im[j] = fmaf(xpm[r0 + j][62], tw1.y, im[j]);
      }
    }
#pragma unroll
    for (int j = 0; j < 4; ++j) irc[r0 + j][k] = make_float2(re[j], -im[j]);
  }
  __syncthreads();
  // H radix-4 stage 1: U_m[rho][kz] = sum_a irc[rho+16a][kz] * (-i)^(a*m)
  {
    const int rho = t >> 4, kz = t & 15;
    float2 v0 = irc[rho][kz], v1 = irc[rho + 16][kz];
    float2 v2 = irc[rho + 32][kz], v3 = irc[rho + 48][kz];
    float t0r = v0.x + v2.x, t0i = v0.y + v2.y;
    float t1r = v0.x - v2.x, t1i = v0.y - v2.y;
    float t2r = v1.x + v3.x, t2i = v1.y + v3.y;
    float t3r = v1.x - v3.x, t3i = v1.y - v3.y;
    U[0][rho][kz] = make_float2(t0r + t2r, t0i + t2i);
    U[2][rho][kz] = make_float2(t0r - t2r, t0i - t2i);
    U[1][rho][kz] = make_float2(t1r + t3i, t1i - t3r);   // t1 - i*t3
    U[3][rho][kz] = make_float2(t1r - t3i, t1i + t3r);   // t1 + i*t3
  }
  __syncthreads();
  // H radix-4 stage 2: X2[ky][kz] = sum_rho e^{-i th ky rho} U_{ky&3}[rho][kz]
  {
    const int ky = t >> 4, kz = t & 15;
    const int m = ky & 3;
    float ar = 0.f, ai = 0.f;
    int idx = 0;
#pragma unroll
    for (int rho = 0; rho < 16; ++rho) {
      float2 wv = tw[idx];                 // conj for e^{-i}
      float2 u = U[m][rho][kz];
      ar = fmaf(u.x, wv.x, fmaf(u.y, wv.y, ar));
      ai = fmaf(u.y, wv.x, fmaf(-u.x, wv.y, ai));
      idx = (idx + ky) & 63;
    }
    T1[(size_t)blk * 256 + t] = make_float2(ar, ai);   // [d][ky][kz]
  }
}

// ---------------- forward: D axis 64 -> 16, block = (b*i, ky) --------------
__global__ __launch_bounds__(256) void k_fwd_d(const float2* __restrict__ T1,
                                               float2* __restrict__ T2) {
  __shared__ float2 s1[64][17];
  __shared__ float2 tw[64];
  const int t = threadIdx.x;
  if (t < 64) { float s, c; sincosf(ANG * (float)t, &s, &c); tw[t] = make_float2(c, s); }
  const int bi = blockIdx.x >> 4, ky = blockIdx.x & 15;
  const float2* src = T1 + (size_t)bi * 16384 + ky * 16;
#pragma unroll
  for (int p = 0; p < 4; ++p) {
    int j = p * 256 + t;
    s1[j >> 4][j & 15] = src[(size_t)(j >> 4) * 256 + (j & 15)];
  }
  __syncthreads();
  const int kx = t >> 4, kz = t & 15;
  float ar = 0.f, ai = 0.f;
  int idx = 0;
#pragma unroll 8
  for (int d = 0; d < 64; ++d) {
    float2 v = s1[d][kz];
    float2 wv = tw[idx];                   // conj for e^{-i th d kx}
    ar = fmaf(v.x, wv.x, fmaf(v.y, wv.y, ar));
    ai = fmaf(v.y, wv.x, fmaf(-v.x, wv.y, ai));
    idx = (idx + kx) & 63;
  }
  T2[(size_t)bi * 4096 + kx * 256 + ky * 16 + kz] = make_float2(ar, ai);
}

// ---------------- channel mix: each weight element read exactly once ------
__global__ __launch_bounds__(256) void k_mix(const float2* __restrict__ T2,
                                             const float* __restrict__ wgt,
                                             float2* __restrict__ MX) {
  __shared__ float2 ts2[4][64][8];         // 16 KB
  const int t = threadIdx.x;
  const int mbase = blockIdx.x * 8;        // 512 blocks x 8 modes
#pragma unroll
  for (int p = 0; p < 8; ++p) {
    int j = p * 256 + t;
    int m = j & 7, i = (j >> 3) & 63, b = j >> 9;
    ts2[b][i][m] = T2[(size_t)(b * 64 + i) * 4096 + mbase + m];
  }
  __syncthreads();
  const int b = t >> 6, o = t & 63;
  float accr[8], acci[8];
#pragma unroll
  for (int m = 0; m < 8; ++m) { accr[m] = 0.f; acci[m] = 0.f; }
  const float* wp0 = wgt + (size_t)o * 4096 + mbase;
#pragma unroll 2
  for (int i = 0; i < 64; ++i) {
    const float* wp = wp0 + (size_t)i * 262144;
    float4 wa = *reinterpret_cast<const float4*>(wp);
    float4 wb = *reinterpret_cast<const float4*>(wp + 4);
    const float4* xv = reinterpret_cast<const float4*>(&ts2[b][i][0]);
    float4 x0 = xv[0], x1 = xv[1], x2 = xv[2], x3 = xv[3];
    accr[0] = fmaf(x0.x, wa.x, accr[0]); acci[0] = fmaf(x0.y, wa.x, acci[0]);
    accr[1] = fmaf(x0.z, wa.y, accr[1]); acci[1] = fmaf(x0.w, wa.y, acci[1]);
    accr[2] = fmaf(x1.x, wa.z, accr[2]); acci[2] = fmaf(x1.y, wa.z, acci[2]);
    accr[3] = fmaf(x1.z, wa.w, accr[3]); acci[3] = fmaf(x1.w, wa.w, acci[3]);
    accr[4] = fmaf(x2.x, wb.x, accr[4]); acci[4] = fmaf(x2.y, wb.x, acci[4]);
    accr[5] = fmaf(x2.z, wb.y, accr[5]); acci[5] = fmaf(x2.w, wb.y, acci[5]);
    accr[6] = fmaf(x3.x, wb.z, accr[6]); acci[6] = fmaf(x3.y, wb.z, acci[6]);
    accr[7] = fmaf(x3.z, wb.w, accr[7]); acci[7] = fmaf(x3.w, wb.w, acci[7]);
  }
  float4* outp = reinterpret_cast<float4*>(MX + (size_t)(b * 64 + o) * 4096 + mbase);
  outp[0] = make_float4(accr[0], acci[0], accr[1], acci[1]);
  outp[1] = make_float4(accr[2], acci[2], accr[3], acci[3]);
  outp[2] = make_float4(accr[4], acci[4], accr[5], acci[5]);
  outp[3] = make_float4(accr[6], acci[6], accr[7], acci[7]);
}

// -------- inverse (fused): D-expand + H radix-4 + W Hermitian radix-4 ------
__global__ __launch_bounds__(256) void k_inv(const float2* __restrict__ MX,
                                             const float* __restrict__ bias,
                                             float* __restrict__ out) {
  __shared__ float2 tw[64];
  __shared__ float2 inb[16][17];
  __shared__ float2 g2[64][17];
  const int t = threadIdx.x;
  const int blk = blockIdx.x;              // (b*64+o)*64 + d
  const int d = blk & 63, bo = blk >> 6;
  if (t < 64) { float s, c; sincosf(ANG * (float)t, &s, &c); tw[t] = make_float2(c, s); }
  __syncthreads();
  // D expand: inb[ky][kz] = sum_kx MX[bo][kx][ky][kz] e^{+i th d kx}
  {
    const float2* src = MX + (size_t)bo * 4096 + t;
    float ar = 0.f, ai = 0.f;
    int idx = 0;
#pragma unroll
    for (int kx = 0; kx < 16; ++kx) {
      float2 v = src[(size_t)kx * 256];
      float2 wv = tw[idx];
      ar = fmaf(v.x, wv.x, fmaf(-v.y, wv.y, ar));
      ai = fmaf(v.x, wv.y, fmaf(v.y, wv.x, ai));
      idx = (idx + d) & 63;
    }
    inb[t >> 4][t & 15] = make_float2(ar, ai);
  }
  __syncthreads();
  // H expand radix-4: h = j + 16a
  {
    const int j = t >> 4, kz = t & 15;
    float2 S[4];
#pragma unroll
    for (int q = 0; q < 4; ++q) S[q] = make_float2(0.f, 0.f);
    int idx = 0;
#pragma unroll
    for (int ky = 0; ky < 16; ++ky) {
      float2 wv = tw[idx];                 // e^{+i th j ky}
      float2 v = inb[ky][kz];
      S[ky & 3].x = fmaf(v.x, wv.x, fmaf(-v.y, wv.y, S[ky & 3].x));
      S[ky & 3].y = fmaf(v.x, wv.y, fmaf(v.y, wv.x, S[ky & 3].y));
      idx = (idx + j) & 63;
    }
    float t0r = S[0].x + S[2].x, t0i = S[0].y + S[2].y;
    float t1r = S[0].x - S[2].x, t1i = S[0].y - S[2].y;
    float t2r = S[1].x + S[3].x, t2i = S[1].y + S[3].y;
    float t3r = S[1].x - S[3].x, t3i = S[1].y - S[3].y;
    float f = (kz == 0) ? 1.f : 2.f;       // pre-double for Hermitian W (not DC)
    g2[j     ][kz] = make_float2(f * (t0r + t2r), f * (t0i + t2i));
    g2[j + 16][kz] = make_float2(f * (t1r - t3i), f * (t1i + t3r));  // t1 + i*t3
    g2[j + 32][kz] = make_float2(f * (t0r - t2r), f * (t0i - t2i));
    g2[j + 48][kz] = make_float2(f * (t1r + t3i), f * (t1i - t3r));  // t1 - i*t3
  }
  __syncthreads();
  // W Hermitian radix-4: w = b + 16a;  x[w] = Re(sum_k g2[h][k] e^{+i th k b} i^{ka})
  {
    const int b = t & 15, hg = t >> 4;
    float twc[16], tws[16];
    int idx = 0;
#pragma unroll
    for (int k = 0; k < 16; ++k) {
      float2 wv = tw[idx];
      twc[k] = wv.x; tws[k] = wv.y;
      idx = (idx + b) & 63;
    }
    const float bv = bias[bo & 63];
    const float scale = 3.814697265625e-06f;   // 1/64^3
    float* og = out + (size_t)blk * 4096;
#pragma unroll
    for (int j2 = 0; j2 < 4; ++j2) {
      const int h = 4 * hg + j2;
      float S0r = 0.f, S2r = 0.f, S1r = 0.f, S1i = 0.f, S3r = 0.f, S3i = 0.f;
#pragma unroll
      for (int k = 0; k < 16; ++k) {
        float2 g = g2[h][k];
        float pr = fmaf(g.x, twc[k], -g.y * tws[k]);
        if ((k & 1) == 0) {                 // even k: imag never needed
          if ((k & 3) == 0) S0r += pr; else S2r += pr;
        } else {
          float pi = fmaf(g.x, tws[k], g.y * twc[k]);
          if ((k & 3) == 1) { S1r += pr; S1i += pi; }
          else              { S3r += pr; S3i += pi; }
        }
      }
      float e0 = S0r + S2r;                 // Re(t0)
      float e1 = S0r - S2r;                 // Re(t1)
      float e2 = S1r + S3r;                 // Re(t2)
      float e3 = S1i - S3i;                 // Im(t3)
      og[h * 64 + b     ] = fmaf(e0 + e2, scale, bv);
      og[h * 64 + b + 16] = fmaf(e1 - e3, scale, bv);
      og[h * 64 + b + 32] = fmaf(e0 - e2, scale, bv);
      og[h * 64 + b + 48] = fmaf(e1 + e3, scale, bv);
    }
  }
}

extern "C" void kernel_launch(void* const* d_in, const int* in_sizes, int n_in,
                              void* d_out, int out_size, void* d_ws, size_t ws_size,
                              hipStream_t stream) {
  const float* x    = (const float*)d_in[0];   // (4,64,64,64,64)
  const float* wgt  = (const float*)d_in[1];   // (64,64,16,16,16)
  const float* bias = (const float*)d_in[2];   // (64,)
  float* out = (float*)d_out;                  // (4,64,64,64,64)

  float* wsf = (float*)d_ws;
  float2* T1 = (float2*)wsf;                       // 33.5 MB
  float2* T2 = (float2*)(wsf + 8388608);           //  8.4 MB
  float2* MX = (float2*)(wsf + 8388608 + 2097152); //  8.4 MB

  k_fwd_hw<<<16384, 256, 0, stream>>>(x, T1);
  k_fwd_d <<<4096,  256, 0, stream>>>(T1, T2);
  k_mix   <<<512,   256, 0, stream>>>(T2, wgt, MX);
  k_inv   <<<16384, 256, 0, stream>>>(MX, bias, out);
}